// Round 12
// baseline (239.853 us; speedup 1.0000x reference)
//
#include <hip/hip_runtime.h>
#include <math.h>

#define NPIX 4096
#define EPSBN 1e-5f

typedef __attribute__((ext_vector_type(8))) short bf16x8;
typedef __attribute__((ext_vector_type(4))) float f32x4;

__device__ __forceinline__ float sigmoidf_(float x) { return 1.0f / (1.0f + expf(-x)); }

__device__ __forceinline__ short f2bf(float f) {
    unsigned u = __float_as_uint(f);
    u += 0x7fffu + ((u >> 16) & 1u);
    return (short)(u >> 16);
}
__device__ __forceinline__ float bf2f(short s) {
    return __uint_as_float(((unsigned)(unsigned short)s) << 16);
}
__device__ __forceinline__ int pk2(float lo, float hi) {
    return (int)(unsigned short)f2bf(lo) | ((int)(unsigned short)f2bf(hi) << 16);
}

__device__ __forceinline__ void gl_lds16(const short* g, short* l) {
    __builtin_amdgcn_global_load_lds(
        (const __attribute__((address_space(1))) void*)g,
        (__attribute__((address_space(3))) void*)l, 16, 0, 0);
}

// ---------------------------------------------------------------------------
// Universal bf16 GEMM-BT:  C = epi( A[M][K] * B[N][K]^T )
// Tile BM x BN, 4 waves, double-buffered LDS, 1-deep prefetch.
// EPI 1: A=xT2 [xh xl] rows (lda=512); K=768 via eA remap k<256?k:k-256.
// EPI 3: gate; also writes per-block column sums to Cv2 (pool stage 1 fused).
// ---------------------------------------------------------------------------
template <int EPI, int BM, int BN>
__global__ __launch_bounds__(256) void gbt_k(
    const short* __restrict__ A, int lda,
    const short* __restrict__ B, int ldb,
    void* __restrict__ Cv, void* __restrict__ Cv2, int Ktot,
    const float* __restrict__ bias, const float* __restrict__ bias2,
    const float* __restrict__ bng, const float* __restrict__ bnb,
    const float* __restrict__ bnm, const float* __restrict__ bnv,
    const short* __restrict__ aux, const float* __restrict__ yrp)
{
    constexpr int FI = BM / 32, FJ = BN / 32;
    constexpr int SA = BM / 64, SB = BN / 64;
    __shared__ alignas(16) short lsA[2 * BM * 32];
    __shared__ alignas(16) short lsB[2 * BN * 32];

    const int tid = threadIdx.x;
    const int l = tid & 63;
    const int wv = tid >> 6;
    const int wm = wv >> 1, wn = wv & 1;
    const int m0 = blockIdx.y * BM;
    const int n0 = blockIdx.x * BN;

    const short* arow[2];
    const short* brow[2];
#pragma unroll
    for (int s = 0; s < SA; ++s) {
        int r = wv * (16 * SA) + s * 16 + (l >> 2);
        int sd = (l & 3) ^ ((r >> 1) & 3);
        if (EPI == 5) {
            int g = m0 + r;
            int p = (g >> 12) * 4356 + (((g & 4095) >> 6) + 1) * 66 + ((g & 63) + 1);
            arow[s] = A + (size_t)p * 256 + (sd << 3);
        } else {
            arow[s] = A + (size_t)(m0 + r) * lda + (sd << 3);
        }
    }
#pragma unroll
    for (int s = 0; s < SB; ++s) {
        int r = wv * (16 * SB) + s * 16 + (l >> 2);
        int sd = (l & 3) ^ ((r >> 1) & 3);
        brow[s] = B + (size_t)(n0 + r) * ldb + (sd << 3);
    }

    const int ks = l >> 4;
    const int lc = l & 15;
    int aoff[FI], boff[FJ];
#pragma unroll
    for (int f = 0; f < FI; ++f) {
        int ra = wm * (BM / 2) + f * 16 + lc;
        aoff[f] = ra * 64 + ((ks ^ ((ra >> 1) & 3)) << 4);
    }
#pragma unroll
    for (int f = 0; f < FJ; ++f) {
        int rb = wn * (BN / 2) + f * 16 + lc;
        boff[f] = rb * 64 + ((ks ^ ((rb >> 1) & 3)) << 4);
    }

    auto stage = [&](int d, int k0l) {
        int eA, eB;
        if (EPI == 5) {
            int t = k0l >> 8, ci0 = k0l & 255;
            eA = ((t / 3) * 66 + (t % 3) - 67) * 256 + ci0;
            eB = t * 65536 + ci0;
        } else if (EPI == 1) {
            eA = (k0l < 256) ? k0l : k0l - 256;   // [xh xh xl] from [xh xl]
            eB = k0l;
        } else {
            eA = k0l; eB = k0l;
        }
        short* dA = lsA + d * (BM * 32) + wv * (SA * 512);
        short* dB = lsB + d * (BN * 32) + wv * (SB * 512);
#pragma unroll
        for (int s = 0; s < SA; ++s) gl_lds16(arow[s] + eA, dA + s * 512);
#pragma unroll
        for (int s = 0; s < SB; ++s) gl_lds16(brow[s] + eB, dB + s * 512);
    };

    f32x4 acc[FI][FJ] = {};
    const int nt = Ktot >> 5;

    stage(0, 0);
    __syncthreads();
    int cur = 0;
    for (int t = 0; t < nt; ++t) {
        if (t + 1 < nt) stage(cur ^ 1, (t + 1) << 5);
        bf16x8 af[FI], bfr[FJ];
#pragma unroll
        for (int f = 0; f < FI; ++f)
            af[f] = *(const bf16x8*)((const char*)lsA + cur * (BM * 64) + aoff[f]);
#pragma unroll
        for (int f = 0; f < FJ; ++f)
            bfr[f] = *(const bf16x8*)((const char*)lsB + cur * (BN * 64) + boff[f]);
#pragma unroll
        for (int i = 0; i < FI; ++i)
#pragma unroll
            for (int j = 0; j < FJ; ++j)
                acc[i][j] = __builtin_amdgcn_mfma_f32_16x16x32_bf16(af[i], bfr[j], acc[i][j], 0, 0, 0);
        __syncthreads();
        cur ^= 1;
    }

    float colsum[FJ < 1 ? 1 : FJ] = {};
    const int lr = (l >> 4) << 2;
#pragma unroll
    for (int i = 0; i < FI; ++i) {
        const int rowl = wm * (BM / 2) + i * 16 + lr;
#pragma unroll
        for (int j = 0; j < FJ; ++j) {
            const int coll = n0 + wn * (BN / 2) + j * 16 + lc;

            float sc = 0.f, tc = 0.f, bi = 0.f;
            if constexpr (EPI == 1) {
                bi = (coll < 128) ? bias[coll] : bias2[coll - 128];
            } else if constexpr (EPI == 3 || EPI == 4 || EPI == 5) {
                sc = bng[coll] * rsqrtf(bnv[coll] + EPSBN);
                tc = bnb[coll] - bnm[coll] * sc;
                bi = bias[coll];
            }

#pragma unroll
            for (int r = 0; r < 4; ++r) {
                const int row = m0 + rowl + r;
                float vvv = acc[i][j][r];
                if constexpr (EPI == 1) {
                    float val = vvv + bi;
                    short hi = f2bf(val);
                    short lo = f2bf(val - bf2f(hi));
                    size_t rb = (size_t)row * 256;
                    if (coll < 128) {
                        short* qb_ = (short*)Cv;
                        qb_[rb + coll] = hi;
                        qb_[rb + 128 + coll] = lo;
                    } else {
                        short* kb_ = (short*)Cv2;
                        int c = coll - 128;
                        kb_[rb + c] = hi;
                        kb_[rb + 128 + c] = lo;
                    }
                } else if constexpr (EPI == 2) {
                    int bb = coll >> 12;
                    ((short*)Cv)[((size_t)bb * 256 + row) * 4096 + (coll & 4095)] = f2bf(vvv + bias[row]);
                } else if constexpr (EPI == 3) {
                    float g = sigmoidf_(fmaxf(sc * (vvv + bi) + tc, 0.f));
                    float fv = bf2f(aux[(size_t)row * 256 + coll]);
                    float yv = fv * g;
                    ((short*)Cv)[(size_t)row * 256 + coll] = f2bf(yv);
                    colsum[j] += yv;
                } else if constexpr (EPI == 4) {
                    float rv = fmaxf(sc * (vvv + bi) + tc, 0.f);
                    int bb = row >> 12, n = row & 4095;
                    int pr = bb * 4356 + ((n >> 6) + 1) * 66 + (n & 63) + 1;
                    ((short*)Cv)[(size_t)pr * 256 + coll] = f2bf(rv);
                } else if constexpr (EPI == 5) {
                    float rv = fmaxf(sc * (vvv + bi) + tc, 0.f);
                    ((short*)Cv)[(size_t)row * 256 + coll] = f2bf(rv);
                } else if constexpr (EPI == 6) {
                    float s6 = bng[row] * rsqrtf(bnv[row] + EPSBN);
                    float t6 = bnb[row] - bnm[row] * s6;
                    int bb = coll >> 12;
                    float yl = fmaxf(s6 * (vvv + bias[row]) + t6, 0.f);
                    float sg = sigmoidf_(yl + yrp[bb * 256 + row]);
                    float fv = bf2f(aux[(size_t)coll * 256 + row]);
                    ((float*)Cv)[((size_t)bb * 256 + row) * 4096 + (coll & 4095)] = fv * sg;
                }
            }
        }
    }

    // ---- EPI 3: fused pool stage 1 — per-block column sums -> Cv2 ----
    if constexpr (EPI == 3) {
        float* lsum = (float*)lsA;   // [64 cols][8 partials], 2 KB
#pragma unroll
        for (int j = 0; j < FJ; ++j) {
            int cl = wn * (BN / 2) + j * 16 + lc;
            lsum[cl * 8 + wm * 4 + ks] = colsum[j];
        }
        __syncthreads();
        if (tid < BN) {
            float s = 0.f;
#pragma unroll
            for (int u = 0; u < 8; ++u) s += lsum[tid * 8 + u];
            ((float*)Cv2)[(size_t)blockIdx.y * 256 + n0 + tid] = s;
        }
    }
}

// ---------------------------------------------------------------------------
// Flash attention v3: swapped QK + K-ROW-PERMUTED staging (no P transpose).
// 512 thr / 8 waves / 32 q per wave / 256 q per block; kv-EIGHTH per block.
// Grid 512 = 16 qblk x 32 combos (batch*8+kvo); 16 iters; 2 blocks/CU.
// LDS K-slot m holds global kv row g(m) = ((m>>2)&3)*8 + (m>>4)*4 + (m&3).
// ---------------------------------------------------------------------------
__global__ __launch_bounds__(512, 2) void flash_k(
    const short* __restrict__ Q, const short* __restrict__ K,
    const short* __restrict__ V, short* __restrict__ Op, float* __restrict__ lp)
{
    __shared__ alignas(16) short smem[32768];
    // BYTES: K dbuf [0, 32768) | V dbuf [32768, 65536)

    const int tid = threadIdx.x;
    const int l = tid & 63;
    const int wv = tid >> 6;              // 0..7
    const int bid = blockIdx.x;
    const int combo = bid & 31;           // batch*8 + kvo  (combo%8 = XCD)
    const int batch = combo >> 3;
    const int kvo = combo & 7;
    const int q0 = (bid >> 5) * 256;
    const int kv0 = kvo * 512;

    const short* Qb = Q + (size_t)batch * 4096 * 256;
    const short* Kb = K + (size_t)batch * 4096 * 256;
    const short* Vb = V + (size_t)batch * 256 * 4096;

    const int lc = l & 15, ks = l >> 4;

    // ---- Q fragments direct from global (B-operand: col=q=lc, k-chunk=ks) ----
    bf16x8 bq[2][8];
#pragma unroll
    for (int f = 0; f < 2; ++f)
#pragma unroll
        for (int cc = 0; cc < 8; ++cc)
            bq[f][cc] = *(const bf16x8*)(Qb +
                (size_t)(q0 + wv * 32 + f * 16 + lc) * 256 + cc * 32 + ks * 8);

    // ---- K/V staging (K rows permuted by g(slot)) ----
    const short* ksrc[2]; short* kdst[2];
    const short* vsrc[2]; short* vdst[2];
#pragma unroll
    for (int i = 0; i < 2; ++i) {
        int slot = wv * 4 + i * 2 + (l >> 5);
        int grow = ((slot >> 2) & 3) * 8 + (slot >> 4) * 4 + (slot & 3);
        int s = l & 31;
        int g = s ^ (slot & 7);
        ksrc[i] = Kb + (size_t)(kv0 + grow) * 256 + g * 8;
        kdst[i] = smem + wv * 1024 + i * 512;
        int c = wv * 32 + i * 16 + (l >> 2);
        int sv = l & 3;
        int gv = sv ^ ((c >> 1) & 3);
        vsrc[i] = Vb + (size_t)c * 4096 + kv0 + gv * 8;
        vdst[i] = smem + 16384 + wv * 1024 + i * 512;
    }
    auto stageKV = [&](int buf, int t) {
#pragma unroll
        for (int i = 0; i < 2; ++i) gl_lds16(ksrc[i] + (size_t)t * 8192, kdst[i] + buf * 8192);
#pragma unroll
        for (int i = 0; i < 2; ++i) gl_lds16(vsrc[i] + t * 32, vdst[i] + buf * 8192);
    };

    stageKV(0, 0);
    __syncthreads();

    const int kro = lc * 512;
    const int kxr = lc & 7;
    const int vb0 = lc * 64 + ((ks ^ ((lc >> 1) & 3)) << 4);

    bf16x8 ones;
#pragma unroll
    for (int e = 0; e < 8; ++e) ones[e] = (short)0x3F80;

    f32x4 acc_o[2][16] = {};
    f32x4 acc_l[2] = {};

    int cur = 0;
    for (int t = 0; t < 16; ++t) {
        if (t + 1 < 16) stageKV(cur ^ 1, t + 1);

        // ---- S^T = K·Q^T (hi/lo 3-term) ----
        const char* kb_ = (const char*)smem + cur * 16384;
        f32x4 s00 = {}, s01 = {}, s10 = {}, s11 = {};
        __builtin_amdgcn_s_setprio(1);
#pragma unroll
        for (int jc = 0; jc < 4; ++jc) {
#pragma unroll
            for (int kvf = 0; kvf < 2; ++kvf) {
                const char* rb_ = kb_ + kro + kvf * 8192;
                bf16x8 kh_ = *(const bf16x8*)(rb_ + ((((jc * 4) + ks) ^ kxr) << 4));
                bf16x8 kl_ = *(const bf16x8*)(rb_ + (((((jc + 4) * 4) + ks) ^ kxr) << 4));
                f32x4& sA = kvf ? s01 : s00;
                f32x4& sB = kvf ? s11 : s10;
                sA = __builtin_amdgcn_mfma_f32_16x16x32_bf16(kh_, bq[0][jc], sA, 0, 0, 0);
                sB = __builtin_amdgcn_mfma_f32_16x16x32_bf16(kh_, bq[1][jc], sB, 0, 0, 0);
                sA = __builtin_amdgcn_mfma_f32_16x16x32_bf16(kl_, bq[0][jc], sA, 0, 0, 0);
                sB = __builtin_amdgcn_mfma_f32_16x16x32_bf16(kl_, bq[1][jc], sB, 0, 0, 0);
                sA = __builtin_amdgcn_mfma_f32_16x16x32_bf16(kh_, bq[0][jc + 4], sA, 0, 0, 0);
                sB = __builtin_amdgcn_mfma_f32_16x16x32_bf16(kh_, bq[1][jc + 4], sB, 0, 0, 0);
            }
        }
        __builtin_amdgcn_s_setprio(0);

        // ---- P = exp(S): registers already in PV A-operand order ----
        bf16x8 pa[2];
#pragma unroll
        for (int f = 0; f < 2; ++f) {
            const f32x4& sa = f ? s10 : s00;   // kv = ks*8 + 0..3
            const f32x4& sb = f ? s11 : s01;   // kv = ks*8 + 4..7
            union { int i4[4]; bf16x8 v; } un;
            un.i4[0] = pk2(__expf(sa[0]), __expf(sa[1]));
            un.i4[1] = pk2(__expf(sa[2]), __expf(sa[3]));
            un.i4[2] = pk2(__expf(sb[0]), __expf(sb[1]));
            un.i4[3] = pk2(__expf(sb[2]), __expf(sb[3]));
            pa[f] = un.v;
        }

        // ---- O += P·V ; l += P·1 ----
        const char* vbb = (const char*)smem + 32768 + cur * 16384;
        __builtin_amdgcn_s_setprio(1);
#pragma unroll
        for (int j = 0; j < 16; ++j) {
            bf16x8 vv = *(const bf16x8*)(vbb + vb0 + j * 1024);
            acc_o[0][j] = __builtin_amdgcn_mfma_f32_16x16x32_bf16(pa[0], vv, acc_o[0][j], 0, 0, 0);
            acc_o[1][j] = __builtin_amdgcn_mfma_f32_16x16x32_bf16(pa[1], vv, acc_o[1][j], 0, 0, 0);
        }
        acc_l[0] = __builtin_amdgcn_mfma_f32_16x16x32_bf16(pa[0], ones, acc_l[0], 0, 0, 0);
        acc_l[1] = __builtin_amdgcn_mfma_f32_16x16x32_bf16(pa[1], ones, acc_l[1], 0, 0, 0);
        __builtin_amdgcn_s_setprio(0);
        __syncthreads();
        cur ^= 1;
    }

    // ---- store unnormalized bf16 partials ----
    short* Ob = Op + ((size_t)combo * 4096 + q0 + wv * 32) * 256;
#pragma unroll
    for (int f = 0; f < 2; ++f)
#pragma unroll
        for (int j = 0; j < 16; ++j)
#pragma unroll
            for (int r = 0; r < 4; ++r)
                Ob[(size_t)(f * 16 + ks * 4 + r) * 256 + j * 16 + lc] = f2bf(acc_o[f][j][r]);
    if (lc == 0) {
        float* lb = lp + (size_t)combo * 4096 + q0 + wv * 32;
#pragma unroll
        for (int f = 0; f < 2; ++f)
#pragma unroll
            for (int r = 0; r < 4; ++r)
                lb[f * 16 + ks * 4 + r] = acc_l[f][r];
    }
}

// featT = (sum of 8 bf16 kvo partials) / (sum of l), cast bf16.
__global__ __launch_bounds__(256) void combine_k(const short* __restrict__ Op,
                                                 const float* __restrict__ lp,
                                                 short* __restrict__ o)
{
    int idx = blockIdx.x * 256 + threadIdx.x;
    size_t e = (size_t)idx * 4;
    int row = (int)(e >> 8);            // (b, q)
    int batch = row >> 12, ql = row & 4095;
    int c = (int)(e & 255);
    size_t lbase = (size_t)batch * 8 * 4096 + ql;
    float lsum = 0.f;
#pragma unroll
    for (int k = 0; k < 8; ++k) lsum += lp[lbase + (size_t)k * 4096];
    float li = 1.0f / lsum;
    size_t base = ((size_t)(batch * 8) * 4096 + ql) * 256 + c;
    float s0 = 0.f, s1 = 0.f, s2 = 0.f, s3 = 0.f;
#pragma unroll
    for (int k = 0; k < 8; ++k) {
        const short4 a = *(const short4*)(Op + base + (size_t)k * 1048576);
        s0 += bf2f(a.x); s1 += bf2f(a.y); s2 += bf2f(a.z); s3 += bf2f(a.w);
    }
    short4 o4;
    o4.x = f2bf(s0 * li);
    o4.y = f2bf(s1 * li);
    o4.z = f2bf(s2 * li);
    o4.w = f2bf(s3 * li);
    *(short4*)(o + (size_t)row * 256 + c) = o4;
}

// ---------------------------------------------------------------------------
// x [B][256][4096] fp32 -> xT2 [(b,n)][512] bf16 hi/lo: [xh(256) xl(256)]
// ---------------------------------------------------------------------------
__global__ __launch_bounds__(256) void transpose_x_k(const float* __restrict__ x,
                                                     short* __restrict__ xT2)
{
    __shared__ float t[64][65];
    const int b = blockIdx.z, c0 = blockIdx.y * 64, n0 = blockIdx.x * 64;
    const int tid = threadIdx.x;
#pragma unroll
    for (int rep = 0; rep < 16; ++rep) {
        int idx = tid + rep * 256;
        int i = idx >> 6, j = idx & 63;
        t[i][j] = x[((size_t)(b * 256 + c0 + i)) * NPIX + n0 + j];
    }
    __syncthreads();
#pragma unroll
    for (int rep = 0; rep < 16; ++rep) {
        int idx = tid + rep * 256;
        int i = idx >> 6, j = idx & 63;
        float v = t[j][i];
        short hi = f2bf(v);
        short lo = f2bf(v - bf2f(hi));
        size_t rb = ((size_t)(b * NPIX + n0 + i)) * 512;
        xT2[rb + c0 + j] = hi;
        xT2[rb + 256 + c0 + j] = lo;
    }
}

// ---------------------------------------------------------------------------
// Merged setup: wq/wk hi-lo-hi, 4 plain cvts, l2w permute. Grid 3584.
// ---------------------------------------------------------------------------
__global__ __launch_bounds__(256) void prep_k(
    const float* __restrict__ wq, const float* __restrict__ wk,
    const float* __restrict__ wvp, const float* __restrict__ d1w,
    const float* __restrict__ l1w, const float* __restrict__ l3w,
    const float* __restrict__ l2w,
    short* __restrict__ wqk3, short* __restrict__ wvb, short* __restrict__ d1wb,
    short* __restrict__ l1wb, short* __restrict__ l3wb, short* __restrict__ w2b)
{
    const int b = blockIdx.x;
    const int tid = threadIdx.x;
    if (b < 256) {
        int idx = b * 256 + tid;
        int o = idx >> 8, c = idx & 255;
        const float* src = (o < 128) ? wq : wk;
        float v = src[(o & 127) * 256 + c];
        short hi = f2bf(v);
        short lo = f2bf(v - bf2f(hi));
        size_t rb = (size_t)o * 768;
        wqk3[rb + c] = hi;
        wqk3[rb + 256 + c] = lo;
        wqk3[rb + 512 + c] = hi;
    } else if (b < 1280) {
        int g = (b - 256) >> 8;
        int i = ((b - 256) & 255) * 256 + tid;
        const float* s = g == 0 ? wvp : g == 1 ? d1w : g == 2 ? l1w : l3w;
        short* d = g == 0 ? wvb : g == 1 ? d1wb : g == 2 ? l1wb : l3wb;
        d[i] = f2bf(s[i]);
    } else {
        int idx = (b - 1280) * 256 + tid;
        int t = idx >> 16;
        int rem = idx & 65535;
        int co = rem >> 8, ci = rem & 255;
        w2b[idx] = f2bf(l2w[((size_t)(co * 256 + ci)) * 9 + t]);
    }
}

// ---------------------------------------------------------------------------
// SE branch with fused pool stage 2: pooled from 32 per-block partials.
// ---------------------------------------------------------------------------
__global__ __launch_bounds__(256) void se_k(
    const float* __restrict__ pp2,
    const float* __restrict__ r1w, const float* __restrict__ r1b,
    const float* __restrict__ g, const float* __restrict__ bb,
    const float* __restrict__ m, const float* __restrict__ vv,
    const float* __restrict__ r2w, const float* __restrict__ r2b,
    float* __restrict__ yr)
{
    const int b = blockIdx.x;
    const int tid = threadIdx.x;
    __shared__ float p[256], hbuf[128];
    float s0 = 0.f;
#pragma unroll
    for (int k = 0; k < 32; ++k)
        s0 += pp2[(size_t)(b * 32 + k) * 256 + tid];
    p[tid] = s0 * (1.0f / NPIX);
    __syncthreads();
    if (tid < 128) {
        float a = r1b[tid];
        for (int ci = 0; ci < 256; ++ci) a = fmaf(r1w[tid * 256 + ci], p[ci], a);
        float s = g[tid] * rsqrtf(vv[tid] + EPSBN);
        float t = bb[tid] - m[tid] * s;
        hbuf[tid] = fmaxf(s * a + t, 0.f);
    }
    __syncthreads();
    float a = r2b[tid];
    for (int c2 = 0; c2 < 128; ++c2) a = fmaf(r2w[tid * 128 + c2], hbuf[c2], a);
    yr[b * 256 + tid] = a;
}

// ---------------------------------------------------------------------------
extern "C" void kernel_launch(void* const* d_in, const int* in_sizes, int n_in,
                              void* d_out, int out_size, void* d_ws, size_t ws_size,
                              hipStream_t stream)
{
    const float* x    = (const float*)d_in[0];
    const float* wq   = (const float*)d_in[1];
    const float* bq   = (const float*)d_in[2];
    const float* wk   = (const float*)d_in[3];
    const float* bk   = (const float*)d_in[4];
    const float* wvp  = (const float*)d_in[5];
    const float* bv   = (const float*)d_in[6];
    const float* d1w  = (const float*)d_in[7];
    const float* d1b  = (const float*)d_in[8];
    const float* bn1g = (const float*)d_in[9];
    const float* bn1b = (const float*)d_in[10];
    const float* bn1m = (const float*)d_in[11];
    const float* bn1v = (const float*)d_in[12];
    const float* lbn1g = (const float*)d_in[13];
    const float* lbn1b = (const float*)d_in[14];
    const float* lbn1m = (const float*)d_in[15];
    const float* lbn1v = (const float*)d_in[16];
    const float* lbn2g = (const float*)d_in[17];
    const float* lbn2b = (const float*)d_in[18];
    const float* lbn2m = (const float*)d_in[19];
    const float* lbn2v = (const float*)d_in[20];
    const float* lbn3g = (const float*)d_in[21];
    const float* lbn3b = (const float*)d_in[22];
    const float* lbn3m = (const float*)d_in[23];
    const float* lbn3v = (const float*)d_in[24];
    const float* l1w  = (const float*)d_in[25];
    const float* l1b  = (const float*)d_in[26];
    const float* l2w  = (const float*)d_in[27];
    const float* l2b  = (const float*)d_in[28];
    const float* l3w  = (const float*)d_in[29];
    const float* l3b  = (const float*)d_in[30];
    const float* r1w  = (const float*)d_in[31];
    const float* r1b  = (const float*)d_in[32];
    const float* rbng = (const float*)d_in[33];
    const float* rbnb = (const float*)d_in[34];
    const float* rbnm = (const float*)d_in[35];
    const float* rbnv = (const float*)d_in[36];
    const float* r2w  = (const float*)d_in[37];
    const float* r2b  = (const float*)d_in[38];

    float* out = (float*)d_out;
    char* wsb = (char*)d_ws;

    // ---- workspace layout ----
    short* xT2  = (short*)(wsb);                    // 0-16 MB (dead after proj)
    short* qbuf = (short*)(wsb + (24ull << 20));    // 24-32
    short* kbuf = (short*)(wsb + (32ull << 20));    // 32-40
    short* vbuf = (short*)(wsb + (40ull << 20));    // 40-48
    short* Opart= (short*)(wsb + (48ull << 20));    // 48-112 bf16 [32][4096][256]
    short* featT= (short*)(wsb + (112ull << 20));   // 112-120
    float* lpart= (float*)(wsb + (120ull << 20));   // [32][4096] 512 KB
    short* yT   = (short*)(wsb + (48ull << 20));    // overlay Opart post-combine
    short* t1pad= (short*)(wsb + (56ull << 20));    // overlay, 8.51 MB
    short* t2T  = (short*)(wsb + (65ull << 20));    // overlay
    short* wqk3 = (short*)(wsb + (121ull << 20));   // 384 KB
    short* wvb  = wqk3 + 196608;                    // 128 KB each
    short* d1wb = wvb + 65536;
    short* l1wb = d1wb + 65536;
    short* l3wb = l1wb + 65536;
    short* w2b  = l3wb + 65536;                     // 1.125 MB
    float* yrb  = (float*)(wsb + (123ull << 20) + (512ull << 10));
    float* ppart2 = yrb + 1024;                     // [128][256] 128 KB

    dim3 blk(256);

    // ---- setup ----
    transpose_x_k<<<dim3(64, 4, 4), blk, 0, stream>>>(x, xT2);
    prep_k<<<3584, blk, 0, stream>>>(wq, wk, wvp, d1w, l1w, l3w, l2w,
                                     wqk3, wvb, d1wb, l1wb, l3wb, w2b);

    // ---- projections ----
    gbt_k<1, 128, 64><<<dim3(4, 128), blk, 0, stream>>>(xT2, 512, wqk3, 768, qbuf, kbuf, 768,
        bq, bk, nullptr, nullptr, nullptr, nullptr, nullptr, nullptr);
    gbt_k<2, 64, 128><<<dim3(128, 4), blk, 0, stream>>>(wvb, 256, xT2, 512, vbuf, nullptr, 256,
        bv, nullptr, nullptr, nullptr, nullptr, nullptr, nullptr, nullptr);

    // ---- fused flash attention (kv-eighth bf16 partials) + combine ----
    flash_k<<<512, dim3(512), 0, stream>>>(qbuf, kbuf, vbuf, Opart, lpart);
    combine_k<<<4096, blk, 0, stream>>>(Opart, lpart, featT);

    // ---- gate: yT = feat * sigmoid(relu(bn1(d1(feat)))); fused pool s1 ----
    gbt_k<3, 128, 64><<<dim3(4, 128), blk, 0, stream>>>(featT, 256, d1wb, 256, yT, ppart2, 256,
        d1b, nullptr, bn1g, bn1b, bn1m, bn1v, featT, nullptr);

    hipMemsetAsync(t1pad, 0, (size_t)4 * 4356 * 256 * 2, stream);

    // ---- SE branch (pool s2 fused into se) ----
    se_k<<<4, blk, 0, stream>>>(ppart2, r1w, r1b, rbng, rbnb, rbnm, rbnv, r2w, r2b, yrb);

    // ---- left branch ----
    gbt_k<4, 128, 64><<<dim3(4, 128), blk, 0, stream>>>(yT, 256, l1wb, 256, t1pad, nullptr, 256,
        l1b, nullptr, lbn1g, lbn1b, lbn1m, lbn1v, nullptr, nullptr);
    gbt_k<5, 128, 64><<<dim3(4, 128), blk, 0, stream>>>(t1pad, 256, w2b, 256, t2T, nullptr, 2304,
        l2b, nullptr, lbn2g, lbn2b, lbn2m, lbn2v, nullptr, nullptr);

    // ---- final: out = feat * sigmoid(relu(bn3(l3(t2))) + yr) ----
    gbt_k<6, 64, 128><<<dim3(128, 4), blk, 0, stream>>>(l3wb, 256, t2T, 256, out, nullptr, 256,
        l3b, nullptr, lbn3g, lbn3b, lbn3m, lbn3v, featT, yrb);
}

// Round 13
// 222.803 us; speedup vs baseline: 1.0765x; 1.0765x over previous
//
#include <hip/hip_runtime.h>
#include <math.h>

#define NPIX 4096
#define EPSBN 1e-5f

typedef __attribute__((ext_vector_type(8))) short bf16x8;
typedef __attribute__((ext_vector_type(4))) float f32x4;

__device__ __forceinline__ float sigmoidf_(float x) { return 1.0f / (1.0f + expf(-x)); }

__device__ __forceinline__ short f2bf(float f) {
    unsigned u = __float_as_uint(f);
    u += 0x7fffu + ((u >> 16) & 1u);
    return (short)(u >> 16);
}
__device__ __forceinline__ float bf2f(short s) {
    return __uint_as_float(((unsigned)(unsigned short)s) << 16);
}
__device__ __forceinline__ int pk2(float lo, float hi) {
    return (int)(unsigned short)f2bf(lo) | ((int)(unsigned short)f2bf(hi) << 16);
}

__device__ __forceinline__ void gl_lds16(const short* g, short* l) {
    __builtin_amdgcn_global_load_lds(
        (const __attribute__((address_space(1))) void*)g,
        (__attribute__((address_space(3))) void*)l, 16, 0, 0);
}

// ---------------------------------------------------------------------------
// Universal bf16 GEMM-BT:  C = epi( A[M][K] * B[N][K]^T )
// Tile BM x BN, 4 waves, double-buffered LDS, 1-deep prefetch.
// EPI 1: A=xT2 [xh xl] rows (lda=512); K=768 via eA remap k<256?k:k-256.
// EPI 3: gate; also writes per-block column sums to Cv2 (pool stage 1 fused).
// ---------------------------------------------------------------------------
template <int EPI, int BM, int BN>
__global__ __launch_bounds__(256) void gbt_k(
    const short* __restrict__ A, int lda,
    const short* __restrict__ B, int ldb,
    void* __restrict__ Cv, void* __restrict__ Cv2, int Ktot,
    const float* __restrict__ bias, const float* __restrict__ bias2,
    const float* __restrict__ bng, const float* __restrict__ bnb,
    const float* __restrict__ bnm, const float* __restrict__ bnv,
    const short* __restrict__ aux, const float* __restrict__ yrp)
{
    constexpr int FI = BM / 32, FJ = BN / 32;
    constexpr int SA = BM / 64, SB = BN / 64;
    __shared__ alignas(16) short lsA[2 * BM * 32];
    __shared__ alignas(16) short lsB[2 * BN * 32];

    const int tid = threadIdx.x;
    const int l = tid & 63;
    const int wv = tid >> 6;
    const int wm = wv >> 1, wn = wv & 1;
    const int m0 = blockIdx.y * BM;
    const int n0 = blockIdx.x * BN;

    const short* arow[2];
    const short* brow[2];
#pragma unroll
    for (int s = 0; s < SA; ++s) {
        int r = wv * (16 * SA) + s * 16 + (l >> 2);
        int sd = (l & 3) ^ ((r >> 1) & 3);
        if (EPI == 5) {
            int g = m0 + r;
            int p = (g >> 12) * 4356 + (((g & 4095) >> 6) + 1) * 66 + ((g & 63) + 1);
            arow[s] = A + (size_t)p * 256 + (sd << 3);
        } else {
            arow[s] = A + (size_t)(m0 + r) * lda + (sd << 3);
        }
    }
#pragma unroll
    for (int s = 0; s < SB; ++s) {
        int r = wv * (16 * SB) + s * 16 + (l >> 2);
        int sd = (l & 3) ^ ((r >> 1) & 3);
        brow[s] = B + (size_t)(n0 + r) * ldb + (sd << 3);
    }

    const int ks = l >> 4;
    const int lc = l & 15;
    int aoff[FI], boff[FJ];
#pragma unroll
    for (int f = 0; f < FI; ++f) {
        int ra = wm * (BM / 2) + f * 16 + lc;
        aoff[f] = ra * 64 + ((ks ^ ((ra >> 1) & 3)) << 4);
    }
#pragma unroll
    for (int f = 0; f < FJ; ++f) {
        int rb = wn * (BN / 2) + f * 16 + lc;
        boff[f] = rb * 64 + ((ks ^ ((rb >> 1) & 3)) << 4);
    }

    auto stage = [&](int d, int k0l) {
        int eA, eB;
        if (EPI == 5) {
            int t = k0l >> 8, ci0 = k0l & 255;
            eA = ((t / 3) * 66 + (t % 3) - 67) * 256 + ci0;
            eB = t * 65536 + ci0;
        } else if (EPI == 1) {
            eA = (k0l < 256) ? k0l : k0l - 256;   // [xh xh xl] from [xh xl]
            eB = k0l;
        } else {
            eA = k0l; eB = k0l;
        }
        short* dA = lsA + d * (BM * 32) + wv * (SA * 512);
        short* dB = lsB + d * (BN * 32) + wv * (SB * 512);
#pragma unroll
        for (int s = 0; s < SA; ++s) gl_lds16(arow[s] + eA, dA + s * 512);
#pragma unroll
        for (int s = 0; s < SB; ++s) gl_lds16(brow[s] + eB, dB + s * 512);
    };

    f32x4 acc[FI][FJ] = {};
    const int nt = Ktot >> 5;

    stage(0, 0);
    __syncthreads();
    int cur = 0;
    for (int t = 0; t < nt; ++t) {
        if (t + 1 < nt) stage(cur ^ 1, (t + 1) << 5);
        bf16x8 af[FI], bfr[FJ];
#pragma unroll
        for (int f = 0; f < FI; ++f)
            af[f] = *(const bf16x8*)((const char*)lsA + cur * (BM * 64) + aoff[f]);
#pragma unroll
        for (int f = 0; f < FJ; ++f)
            bfr[f] = *(const bf16x8*)((const char*)lsB + cur * (BN * 64) + boff[f]);
#pragma unroll
        for (int i = 0; i < FI; ++i)
#pragma unroll
            for (int j = 0; j < FJ; ++j)
                acc[i][j] = __builtin_amdgcn_mfma_f32_16x16x32_bf16(af[i], bfr[j], acc[i][j], 0, 0, 0);
        __syncthreads();
        cur ^= 1;
    }

    float colsum[FJ < 1 ? 1 : FJ] = {};
    const int lr = (l >> 4) << 2;
#pragma unroll
    for (int i = 0; i < FI; ++i) {
        const int rowl = wm * (BM / 2) + i * 16 + lr;
#pragma unroll
        for (int j = 0; j < FJ; ++j) {
            const int coll = n0 + wn * (BN / 2) + j * 16 + lc;

            float sc = 0.f, tc = 0.f, bi = 0.f;
            if constexpr (EPI == 1) {
                bi = (coll < 128) ? bias[coll] : bias2[coll - 128];
            } else if constexpr (EPI == 3 || EPI == 4 || EPI == 5) {
                sc = bng[coll] * rsqrtf(bnv[coll] + EPSBN);
                tc = bnb[coll] - bnm[coll] * sc;
                bi = bias[coll];
            }

#pragma unroll
            for (int r = 0; r < 4; ++r) {
                const int row = m0 + rowl + r;
                float vvv = acc[i][j][r];
                if constexpr (EPI == 1) {
                    float val = vvv + bi;
                    short hi = f2bf(val);
                    short lo = f2bf(val - bf2f(hi));
                    size_t rb = (size_t)row * 256;
                    if (coll < 128) {
                        short* qb_ = (short*)Cv;
                        qb_[rb + coll] = hi;
                        qb_[rb + 128 + coll] = lo;
                    } else {
                        short* kb_ = (short*)Cv2;
                        int c = coll - 128;
                        kb_[rb + c] = hi;
                        kb_[rb + 128 + c] = lo;
                    }
                } else if constexpr (EPI == 2) {
                    int bb = coll >> 12;
                    ((short*)Cv)[((size_t)bb * 256 + row) * 4096 + (coll & 4095)] = f2bf(vvv + bias[row]);
                } else if constexpr (EPI == 3) {
                    float g = sigmoidf_(fmaxf(sc * (vvv + bi) + tc, 0.f));
                    float fv = bf2f(aux[(size_t)row * 256 + coll]);
                    float yv = fv * g;
                    ((short*)Cv)[(size_t)row * 256 + coll] = f2bf(yv);
                    colsum[j] += yv;
                } else if constexpr (EPI == 4) {
                    float rv = fmaxf(sc * (vvv + bi) + tc, 0.f);
                    int bb = row >> 12, n = row & 4095;
                    int pr = bb * 4356 + ((n >> 6) + 1) * 66 + (n & 63) + 1;
                    ((short*)Cv)[(size_t)pr * 256 + coll] = f2bf(rv);
                } else if constexpr (EPI == 5) {
                    float rv = fmaxf(sc * (vvv + bi) + tc, 0.f);
                    ((short*)Cv)[(size_t)row * 256 + coll] = f2bf(rv);
                } else if constexpr (EPI == 6) {
                    float s6 = bng[row] * rsqrtf(bnv[row] + EPSBN);
                    float t6 = bnb[row] - bnm[row] * s6;
                    int bb = coll >> 12;
                    float yl = fmaxf(s6 * (vvv + bias[row]) + t6, 0.f);
                    float sg = sigmoidf_(yl + yrp[bb * 256 + row]);
                    float fv = bf2f(aux[(size_t)coll * 256 + row]);
                    ((float*)Cv)[((size_t)bb * 256 + row) * 4096 + (coll & 4095)] = fv * sg;
                }
            }
        }
    }

    // ---- EPI 3: fused pool stage 1 — per-block column sums -> Cv2 ----
    if constexpr (EPI == 3) {
        float* lsum = (float*)lsA;   // [64 cols][8 partials], 2 KB
#pragma unroll
        for (int j = 0; j < FJ; ++j) {
            int cl = wn * (BN / 2) + j * 16 + lc;
            lsum[cl * 8 + wm * 4 + ks] = colsum[j];
        }
        __syncthreads();
        if (tid < BN) {
            float s = 0.f;
#pragma unroll
            for (int u = 0; u < 8; ++u) s += lsum[tid * 8 + u];
            ((float*)Cv2)[(size_t)blockIdx.y * 256 + n0 + tid] = s;
        }
    }
}

// ---------------------------------------------------------------------------
// Flash attention v3 (round-11 config): swapped QK + K-ROW-PERMUTED staging
// (no P transpose). 512 thr / 8 waves / 32 q per wave / 256 q per block.
// Grid 256 = 16 qblk x 16 combos (batch*4+kvq); kv-quarter, 32 iters.
// LDS K-slot m holds global kv row g(m) = ((m>>2)&3)*8 + (m>>4)*4 + (m&3).
// ---------------------------------------------------------------------------
__global__ __launch_bounds__(512, 2) void flash_k(
    const short* __restrict__ Q, const short* __restrict__ K,
    const short* __restrict__ V, short* __restrict__ Op, float* __restrict__ lp)
{
    __shared__ alignas(16) short smem[32768];
    // BYTES: K dbuf [0, 32768) | V dbuf [32768, 65536)

    const int tid = threadIdx.x;
    const int l = tid & 63;
    const int wv = tid >> 6;              // 0..7
    const int bid = blockIdx.x;
    const int combo = bid & 15;           // batch*4 + kvq
    const int batch = combo >> 2;
    const int kvq = combo & 3;
    const int q0 = (bid >> 4) * 256;
    const int kv0 = kvq * 1024;

    const short* Qb = Q + (size_t)batch * 4096 * 256;
    const short* Kb = K + (size_t)batch * 4096 * 256;
    const short* Vb = V + (size_t)batch * 256 * 4096;

    const int lc = l & 15, ks = l >> 4;

    // ---- Q fragments direct from global (B-operand: col=q=lc, k-chunk=ks) ----
    bf16x8 bq[2][8];
#pragma unroll
    for (int f = 0; f < 2; ++f)
#pragma unroll
        for (int cc = 0; cc < 8; ++cc)
            bq[f][cc] = *(const bf16x8*)(Qb +
                (size_t)(q0 + wv * 32 + f * 16 + lc) * 256 + cc * 32 + ks * 8);

    // ---- K/V staging (K rows permuted by g(slot)) ----
    const short* ksrc[2]; short* kdst[2];
    const short* vsrc[2]; short* vdst[2];
#pragma unroll
    for (int i = 0; i < 2; ++i) {
        int slot = wv * 4 + i * 2 + (l >> 5);
        int grow = ((slot >> 2) & 3) * 8 + (slot >> 4) * 4 + (slot & 3);
        int s = l & 31;
        int g = s ^ (slot & 7);
        ksrc[i] = Kb + (size_t)(kv0 + grow) * 256 + g * 8;
        kdst[i] = smem + wv * 1024 + i * 512;
        int c = wv * 32 + i * 16 + (l >> 2);
        int sv = l & 3;
        int gv = sv ^ ((c >> 1) & 3);
        vsrc[i] = Vb + (size_t)c * 4096 + kv0 + gv * 8;
        vdst[i] = smem + 16384 + wv * 1024 + i * 512;
    }
    auto stageKV = [&](int buf, int t) {
#pragma unroll
        for (int i = 0; i < 2; ++i) gl_lds16(ksrc[i] + (size_t)t * 8192, kdst[i] + buf * 8192);
#pragma unroll
        for (int i = 0; i < 2; ++i) gl_lds16(vsrc[i] + t * 32, vdst[i] + buf * 8192);
    };

    stageKV(0, 0);
    __syncthreads();

    const int kro = lc * 512;
    const int kxr = lc & 7;
    const int vb0 = lc * 64 + ((ks ^ ((lc >> 1) & 3)) << 4);

    bf16x8 ones;
#pragma unroll
    for (int e = 0; e < 8; ++e) ones[e] = (short)0x3F80;

    f32x4 acc_o[2][16] = {};
    f32x4 acc_l[2] = {};

    int cur = 0;
    for (int t = 0; t < 32; ++t) {
        if (t + 1 < 32) stageKV(cur ^ 1, t + 1);

        // ---- S^T = K·Q^T (hi/lo 3-term) ----
        const char* kb_ = (const char*)smem + cur * 16384;
        f32x4 s00 = {}, s01 = {}, s10 = {}, s11 = {};
        __builtin_amdgcn_s_setprio(1);
#pragma unroll
        for (int jc = 0; jc < 4; ++jc) {
#pragma unroll
            for (int kvf = 0; kvf < 2; ++kvf) {
                const char* rb_ = kb_ + kro + kvf * 8192;
                bf16x8 kh_ = *(const bf16x8*)(rb_ + ((((jc * 4) + ks) ^ kxr) << 4));
                bf16x8 kl_ = *(const bf16x8*)(rb_ + (((((jc + 4) * 4) + ks) ^ kxr) << 4));
                f32x4& sA = kvf ? s01 : s00;
                f32x4& sB = kvf ? s11 : s10;
                sA = __builtin_amdgcn_mfma_f32_16x16x32_bf16(kh_, bq[0][jc], sA, 0, 0, 0);
                sB = __builtin_amdgcn_mfma_f32_16x16x32_bf16(kh_, bq[1][jc], sB, 0, 0, 0);
                sA = __builtin_amdgcn_mfma_f32_16x16x32_bf16(kl_, bq[0][jc], sA, 0, 0, 0);
                sB = __builtin_amdgcn_mfma_f32_16x16x32_bf16(kl_, bq[1][jc], sB, 0, 0, 0);
                sA = __builtin_amdgcn_mfma_f32_16x16x32_bf16(kh_, bq[0][jc + 4], sA, 0, 0, 0);
                sB = __builtin_amdgcn_mfma_f32_16x16x32_bf16(kh_, bq[1][jc + 4], sB, 0, 0, 0);
            }
        }
        __builtin_amdgcn_s_setprio(0);

        // ---- P = exp(S): registers already in PV A-operand order ----
        bf16x8 pa[2];
#pragma unroll
        for (int f = 0; f < 2; ++f) {
            const f32x4& sa = f ? s10 : s00;   // kv = ks*8 + 0..3
            const f32x4& sb = f ? s11 : s01;   // kv = ks*8 + 4..7
            union { int i4[4]; bf16x8 v; } un;
            un.i4[0] = pk2(__expf(sa[0]), __expf(sa[1]));
            un.i4[1] = pk2(__expf(sa[2]), __expf(sa[3]));
            un.i4[2] = pk2(__expf(sb[0]), __expf(sb[1]));
            un.i4[3] = pk2(__expf(sb[2]), __expf(sb[3]));
            pa[f] = un.v;
        }

        // ---- O += P·V ; l += P·1 ----
        const char* vbb = (const char*)smem + 32768 + cur * 16384;
        __builtin_amdgcn_s_setprio(1);
#pragma unroll
        for (int j = 0; j < 16; ++j) {
            bf16x8 vv = *(const bf16x8*)(vbb + vb0 + j * 1024);
            acc_o[0][j] = __builtin_amdgcn_mfma_f32_16x16x32_bf16(pa[0], vv, acc_o[0][j], 0, 0, 0);
            acc_o[1][j] = __builtin_amdgcn_mfma_f32_16x16x32_bf16(pa[1], vv, acc_o[1][j], 0, 0, 0);
        }
        acc_l[0] = __builtin_amdgcn_mfma_f32_16x16x32_bf16(pa[0], ones, acc_l[0], 0, 0, 0);
        acc_l[1] = __builtin_amdgcn_mfma_f32_16x16x32_bf16(pa[1], ones, acc_l[1], 0, 0, 0);
        __builtin_amdgcn_s_setprio(0);
        __syncthreads();
        cur ^= 1;
    }

    // ---- store unnormalized bf16 partials ----
    short* Ob = Op + ((size_t)combo * 4096 + q0 + wv * 32) * 256;
#pragma unroll
    for (int f = 0; f < 2; ++f)
#pragma unroll
        for (int j = 0; j < 16; ++j)
#pragma unroll
            for (int r = 0; r < 4; ++r)
                Ob[(size_t)(f * 16 + ks * 4 + r) * 256 + j * 16 + lc] = f2bf(acc_o[f][j][r]);
    if (lc == 0) {
        float* lb = lp + (size_t)combo * 4096 + q0 + wv * 32;
#pragma unroll
        for (int f = 0; f < 2; ++f)
#pragma unroll
            for (int r = 0; r < 4; ++r)
                lb[f * 16 + ks * 4 + r] = acc_l[f][r];
    }
}

// featT = (sum of 4 bf16 kvq partials) / (sum of l), cast bf16.
__global__ __launch_bounds__(256) void combine_k(const short* __restrict__ Op,
                                                 const float* __restrict__ lp,
                                                 short* __restrict__ o)
{
    int idx = blockIdx.x * 256 + threadIdx.x;
    size_t e = (size_t)idx * 4;
    int row = (int)(e >> 8);            // (b, q)
    int batch = row >> 12, ql = row & 4095;
    int c = (int)(e & 255);
    size_t lbase = (size_t)batch * 4 * 4096 + ql;
    float li = 1.0f / (lp[lbase] + lp[lbase + 4096] + lp[lbase + 8192] + lp[lbase + 12288]);
    size_t base = ((size_t)(batch * 4) * 4096 + ql) * 256 + c;
    const short4 a = *(const short4*)(Op + base);
    const short4 b = *(const short4*)(Op + base + 1048576);
    const short4 cc = *(const short4*)(Op + base + 2097152);
    const short4 d = *(const short4*)(Op + base + 3145728);
    short4 o4;
    o4.x = f2bf((bf2f(a.x) + bf2f(b.x) + bf2f(cc.x) + bf2f(d.x)) * li);
    o4.y = f2bf((bf2f(a.y) + bf2f(b.y) + bf2f(cc.y) + bf2f(d.y)) * li);
    o4.z = f2bf((bf2f(a.z) + bf2f(b.z) + bf2f(cc.z) + bf2f(d.z)) * li);
    o4.w = f2bf((bf2f(a.w) + bf2f(b.w) + bf2f(cc.w) + bf2f(d.w)) * li);
    *(short4*)(o + (size_t)row * 256 + c) = o4;
}

// ---------------------------------------------------------------------------
// x [B][256][4096] fp32 -> xT2 [(b,n)][512] bf16 hi/lo: [xh(256) xl(256)]
// ---------------------------------------------------------------------------
__global__ __launch_bounds__(256) void transpose_x_k(const float* __restrict__ x,
                                                     short* __restrict__ xT2)
{
    __shared__ float t[64][65];
    const int b = blockIdx.z, c0 = blockIdx.y * 64, n0 = blockIdx.x * 64;
    const int tid = threadIdx.x;
#pragma unroll
    for (int rep = 0; rep < 16; ++rep) {
        int idx = tid + rep * 256;
        int i = idx >> 6, j = idx & 63;
        t[i][j] = x[((size_t)(b * 256 + c0 + i)) * NPIX + n0 + j];
    }
    __syncthreads();
#pragma unroll
    for (int rep = 0; rep < 16; ++rep) {
        int idx = tid + rep * 256;
        int i = idx >> 6, j = idx & 63;
        float v = t[j][i];
        short hi = f2bf(v);
        short lo = f2bf(v - bf2f(hi));
        size_t rb = ((size_t)(b * NPIX + n0 + i)) * 512;
        xT2[rb + c0 + j] = hi;
        xT2[rb + 256 + c0 + j] = lo;
    }
}

// ---------------------------------------------------------------------------
// Merged setup: wq/wk hi-lo-hi, 4 plain cvts, l2w permute. Grid 3584.
// ---------------------------------------------------------------------------
__global__ __launch_bounds__(256) void prep_k(
    const float* __restrict__ wq, const float* __restrict__ wk,
    const float* __restrict__ wvp, const float* __restrict__ d1w,
    const float* __restrict__ l1w, const float* __restrict__ l3w,
    const float* __restrict__ l2w,
    short* __restrict__ wqk3, short* __restrict__ wvb, short* __restrict__ d1wb,
    short* __restrict__ l1wb, short* __restrict__ l3wb, short* __restrict__ w2b)
{
    const int b = blockIdx.x;
    const int tid = threadIdx.x;
    if (b < 256) {
        int idx = b * 256 + tid;
        int o = idx >> 8, c = idx & 255;
        const float* src = (o < 128) ? wq : wk;
        float v = src[(o & 127) * 256 + c];
        short hi = f2bf(v);
        short lo = f2bf(v - bf2f(hi));
        size_t rb = (size_t)o * 768;
        wqk3[rb + c] = hi;
        wqk3[rb + 256 + c] = lo;
        wqk3[rb + 512 + c] = hi;
    } else if (b < 1280) {
        int g = (b - 256) >> 8;
        int i = ((b - 256) & 255) * 256 + tid;
        const float* s = g == 0 ? wvp : g == 1 ? d1w : g == 2 ? l1w : l3w;
        short* d = g == 0 ? wvb : g == 1 ? d1wb : g == 2 ? l1wb : l3wb;
        d[i] = f2bf(s[i]);
    } else {
        int idx = (b - 1280) * 256 + tid;
        int t = idx >> 16;
        int rem = idx & 65535;
        int co = rem >> 8, ci = rem & 255;
        w2b[idx] = f2bf(l2w[((size_t)(co * 256 + ci)) * 9 + t]);
    }
}

// ---------------------------------------------------------------------------
// SE branch with fused pool stage 2: pooled from 32 per-block partials.
// ---------------------------------------------------------------------------
__global__ __launch_bounds__(256) void se_k(
    const float* __restrict__ pp2,
    const float* __restrict__ r1w, const float* __restrict__ r1b,
    const float* __restrict__ g, const float* __restrict__ bb,
    const float* __restrict__ m, const float* __restrict__ vv,
    const float* __restrict__ r2w, const float* __restrict__ r2b,
    float* __restrict__ yr)
{
    const int b = blockIdx.x;
    const int tid = threadIdx.x;
    __shared__ float p[256], hbuf[128];
    float s0 = 0.f;
#pragma unroll
    for (int k = 0; k < 32; ++k)
        s0 += pp2[(size_t)(b * 32 + k) * 256 + tid];
    p[tid] = s0 * (1.0f / NPIX);
    __syncthreads();
    if (tid < 128) {
        float a = r1b[tid];
        for (int ci = 0; ci < 256; ++ci) a = fmaf(r1w[tid * 256 + ci], p[ci], a);
        float s = g[tid] * rsqrtf(vv[tid] + EPSBN);
        float t = bb[tid] - m[tid] * s;
        hbuf[tid] = fmaxf(s * a + t, 0.f);
    }
    __syncthreads();
    float a = r2b[tid];
    for (int c2 = 0; c2 < 128; ++c2) a = fmaf(r2w[tid * 128 + c2], hbuf[c2], a);
    yr[b * 256 + tid] = a;
}

// ---------------------------------------------------------------------------
extern "C" void kernel_launch(void* const* d_in, const int* in_sizes, int n_in,
                              void* d_out, int out_size, void* d_ws, size_t ws_size,
                              hipStream_t stream)
{
    const float* x    = (const float*)d_in[0];
    const float* wq   = (const float*)d_in[1];
    const float* bq   = (const float*)d_in[2];
    const float* wk   = (const float*)d_in[3];
    const float* bk   = (const float*)d_in[4];
    const float* wvp  = (const float*)d_in[5];
    const float* bv   = (const float*)d_in[6];
    const float* d1w  = (const float*)d_in[7];
    const float* d1b  = (const float*)d_in[8];
    const float* bn1g = (const float*)d_in[9];
    const float* bn1b = (const float*)d_in[10];
    const float* bn1m = (const float*)d_in[11];
    const float* bn1v = (const float*)d_in[12];
    const float* lbn1g = (const float*)d_in[13];
    const float* lbn1b = (const float*)d_in[14];
    const float* lbn1m = (const float*)d_in[15];
    const float* lbn1v = (const float*)d_in[16];
    const float* lbn2g = (const float*)d_in[17];
    const float* lbn2b = (const float*)d_in[18];
    const float* lbn2m = (const float*)d_in[19];
    const float* lbn2v = (const float*)d_in[20];
    const float* lbn3g = (const float*)d_in[21];
    const float* lbn3b = (const float*)d_in[22];
    const float* lbn3m = (const float*)d_in[23];
    const float* lbn3v = (const float*)d_in[24];
    const float* l1w  = (const float*)d_in[25];
    const float* l1b  = (const float*)d_in[26];
    const float* l2w  = (const float*)d_in[27];
    const float* l2b  = (const float*)d_in[28];
    const float* l3w  = (const float*)d_in[29];
    const float* l3b  = (const float*)d_in[30];
    const float* r1w  = (const float*)d_in[31];
    const float* r1b  = (const float*)d_in[32];
    const float* rbng = (const float*)d_in[33];
    const float* rbnb = (const float*)d_in[34];
    const float* rbnm = (const float*)d_in[35];
    const float* rbnv = (const float*)d_in[36];
    const float* r2w  = (const float*)d_in[37];
    const float* r2b  = (const float*)d_in[38];

    float* out = (float*)d_out;
    char* wsb = (char*)d_ws;

    // ---- workspace layout ----
    short* xT2  = (short*)(wsb);                    // 0-16 MB (dead after proj)
    short* qbuf = (short*)(wsb + (24ull << 20));    // 24-32
    short* kbuf = (short*)(wsb + (32ull << 20));    // 32-40
    short* vbuf = (short*)(wsb + (40ull << 20));    // 40-48
    short* Opart= (short*)(wsb + (48ull << 20));    // 48-80 bf16 [16][4096][256]
    short* featT= (short*)(wsb + (112ull << 20));   // 112-120
    float* lpart= (float*)(wsb + (120ull << 20));   // [16][4096] 256 KB
    short* yT   = (short*)(wsb + (48ull << 20));    // overlay Opart post-combine
    short* t1pad= (short*)(wsb + (56ull << 20));    // overlay, 8.51 MB
    short* t2T  = (short*)(wsb + (65ull << 20));    // overlay
    short* wqk3 = (short*)(wsb + (121ull << 20));   // 384 KB
    short* wvb  = wqk3 + 196608;                    // 128 KB each
    short* d1wb = wvb + 65536;
    short* l1wb = d1wb + 65536;
    short* l3wb = l1wb + 65536;
    short* w2b  = l3wb + 65536;                     // 1.125 MB
    float* yrb  = (float*)(wsb + (123ull << 20) + (512ull << 10));
    float* ppart2 = yrb + 1024;                     // [128][256] 128 KB

    dim3 blk(256);

    // ---- setup ----
    transpose_x_k<<<dim3(64, 4, 4), blk, 0, stream>>>(x, xT2);
    prep_k<<<3584, blk, 0, stream>>>(wq, wk, wvp, d1w, l1w, l3w, l2w,
                                     wqk3, wvb, d1wb, l1wb, l3wb, w2b);

    // ---- projections ----
    gbt_k<1, 128, 64><<<dim3(4, 128), blk, 0, stream>>>(xT2, 512, wqk3, 768, qbuf, kbuf, 768,
        bq, bk, nullptr, nullptr, nullptr, nullptr, nullptr, nullptr);
    gbt_k<2, 64, 128><<<dim3(128, 4), blk, 0, stream>>>(wvb, 256, xT2, 512, vbuf, nullptr, 256,
        bv, nullptr, nullptr, nullptr, nullptr, nullptr, nullptr, nullptr);

    // ---- fused flash attention (kv-quarter bf16 partials) + combine ----
    flash_k<<<256, dim3(512), 0, stream>>>(qbuf, kbuf, vbuf, Opart, lpart);
    combine_k<<<4096, blk, 0, stream>>>(Opart, lpart, featT);

    // ---- gate: yT = feat * sigmoid(relu(bn1(d1(feat)))); fused pool s1 ----
    gbt_k<3, 128, 64><<<dim3(4, 128), blk, 0, stream>>>(featT, 256, d1wb, 256, yT, ppart2, 256,
        d1b, nullptr, bn1g, bn1b, bn1m, bn1v, featT, nullptr);

    hipMemsetAsync(t1pad, 0, (size_t)4 * 4356 * 256 * 2, stream);

    // ---- SE branch (pool s2 fused into se) ----
    se_k<<<4, blk, 0, stream>>>(ppart2, r1w, r1b, rbng, rbnb, rbnm, rbnv, r2w, r2b, yrb);

    // ---- left branch ----
    gbt_k<4, 128, 64><<<dim3(4, 128), blk, 0, stream>>>(yT, 256, l1wb, 256, t1pad, nullptr, 256,
        l1b, nullptr, lbn1g, lbn1b, lbn1m, lbn1v, nullptr, nullptr);
    gbt_k<5, 128, 64><<<dim3(4, 128), blk, 0, stream>>>(t1pad, 256, w2b, 256, t2T, nullptr, 2304,
        l2b, nullptr, lbn2g, lbn2b, lbn2m, lbn2v, nullptr, nullptr);

    // ---- final: out = feat * sigmoid(relu(bn3(l3(t2))) + yr) ----
    gbt_k<6, 64, 128><<<dim3(128, 4), blk, 0, stream>>>(l3wb, 256, t2T, 256, out, nullptr, 256,
        l3b, nullptr, lbn3g, lbn3b, lbn3m, lbn3v, featT, yrb);
}

// Round 15
// 217.614 us; speedup vs baseline: 1.1022x; 1.0238x over previous
//
#include <hip/hip_runtime.h>
#include <math.h>

#define NPIX 4096
#define EPSBN 1e-5f

typedef __attribute__((ext_vector_type(8))) short bf16x8;
typedef __attribute__((ext_vector_type(4))) float f32x4;

__device__ __forceinline__ float sigmoidf_(float x) { return 1.0f / (1.0f + expf(-x)); }

__device__ __forceinline__ short f2bf(float f) {
    unsigned u = __float_as_uint(f);
    u += 0x7fffu + ((u >> 16) & 1u);
    return (short)(u >> 16);
}
__device__ __forceinline__ float bf2f(short s) {
    return __uint_as_float(((unsigned)(unsigned short)s) << 16);
}
__device__ __forceinline__ int pk2(float lo, float hi) {
    return (int)(unsigned short)f2bf(lo) | ((int)(unsigned short)f2bf(hi) << 16);
}

__device__ __forceinline__ void gl_lds16(const short* g, short* l) {
    __builtin_amdgcn_global_load_lds(
        (const __attribute__((address_space(1))) void*)g,
        (__attribute__((address_space(3))) void*)l, 16, 0, 0);
}

// ---------------------------------------------------------------------------
// Universal bf16 GEMM-BT:  C = epi( A[M][K] * B[N][K]^T )
// Tile BM x BN, 4 waves, double-buffered LDS, 1-deep prefetch.
// EPI 1: A=xT2 [xh xl] rows (lda=512); K=768 via eA remap k<256?k:k-256.
// EPI 3: gate; also writes per-block column sums to Cv2 (pool stage 1 fused).
// ---------------------------------------------------------------------------
template <int EPI, int BM, int BN>
__global__ __launch_bounds__(256) void gbt_k(
    const short* __restrict__ A, int lda,
    const short* __restrict__ B, int ldb,
    void* __restrict__ Cv, void* __restrict__ Cv2, int Ktot,
    const float* __restrict__ bias, const float* __restrict__ bias2,
    const float* __restrict__ bng, const float* __restrict__ bnb,
    const float* __restrict__ bnm, const float* __restrict__ bnv,
    const short* __restrict__ aux, const float* __restrict__ yrp)
{
    constexpr int FI = BM / 32, FJ = BN / 32;
    constexpr int SA = BM / 64, SB = BN / 64;
    __shared__ alignas(16) short lsA[2 * BM * 32];
    __shared__ alignas(16) short lsB[2 * BN * 32];

    const int tid = threadIdx.x;
    const int l = tid & 63;
    const int wv = tid >> 6;
    const int wm = wv >> 1, wn = wv & 1;
    const int m0 = blockIdx.y * BM;
    const int n0 = blockIdx.x * BN;

    const short* arow[2];
    const short* brow[2];
#pragma unroll
    for (int s = 0; s < SA; ++s) {
        int r = wv * (16 * SA) + s * 16 + (l >> 2);
        int sd = (l & 3) ^ ((r >> 1) & 3);
        if (EPI == 5) {
            int g = m0 + r;
            int p = (g >> 12) * 4356 + (((g & 4095) >> 6) + 1) * 66 + ((g & 63) + 1);
            arow[s] = A + (size_t)p * 256 + (sd << 3);
        } else {
            arow[s] = A + (size_t)(m0 + r) * lda + (sd << 3);
        }
    }
#pragma unroll
    for (int s = 0; s < SB; ++s) {
        int r = wv * (16 * SB) + s * 16 + (l >> 2);
        int sd = (l & 3) ^ ((r >> 1) & 3);
        brow[s] = B + (size_t)(n0 + r) * ldb + (sd << 3);
    }

    const int ks = l >> 4;
    const int lc = l & 15;
    int aoff[FI], boff[FJ];
#pragma unroll
    for (int f = 0; f < FI; ++f) {
        int ra = wm * (BM / 2) + f * 16 + lc;
        aoff[f] = ra * 64 + ((ks ^ ((ra >> 1) & 3)) << 4);
    }
#pragma unroll
    for (int f = 0; f < FJ; ++f) {
        int rb = wn * (BN / 2) + f * 16 + lc;
        boff[f] = rb * 64 + ((ks ^ ((rb >> 1) & 3)) << 4);
    }

    auto stage = [&](int d, int k0l) {
        int eA, eB;
        if (EPI == 5) {
            int t = k0l >> 8, ci0 = k0l & 255;
            eA = ((t / 3) * 66 + (t % 3) - 67) * 256 + ci0;
            eB = t * 65536 + ci0;
        } else if (EPI == 1) {
            eA = (k0l < 256) ? k0l : k0l - 256;   // [xh xh xl] from [xh xl]
            eB = k0l;
        } else {
            eA = k0l; eB = k0l;
        }
        short* dA = lsA + d * (BM * 32) + wv * (SA * 512);
        short* dB = lsB + d * (BN * 32) + wv * (SB * 512);
#pragma unroll
        for (int s = 0; s < SA; ++s) gl_lds16(arow[s] + eA, dA + s * 512);
#pragma unroll
        for (int s = 0; s < SB; ++s) gl_lds16(brow[s] + eB, dB + s * 512);
    };

    f32x4 acc[FI][FJ] = {};
    const int nt = Ktot >> 5;

    stage(0, 0);
    __syncthreads();
    int cur = 0;
    for (int t = 0; t < nt; ++t) {
        if (t + 1 < nt) stage(cur ^ 1, (t + 1) << 5);
        bf16x8 af[FI], bfr[FJ];
#pragma unroll
        for (int f = 0; f < FI; ++f)
            af[f] = *(const bf16x8*)((const char*)lsA + cur * (BM * 64) + aoff[f]);
#pragma unroll
        for (int f = 0; f < FJ; ++f)
            bfr[f] = *(const bf16x8*)((const char*)lsB + cur * (BN * 64) + boff[f]);
#pragma unroll
        for (int i = 0; i < FI; ++i)
#pragma unroll
            for (int j = 0; j < FJ; ++j)
                acc[i][j] = __builtin_amdgcn_mfma_f32_16x16x32_bf16(af[i], bfr[j], acc[i][j], 0, 0, 0);
        __syncthreads();
        cur ^= 1;
    }

    float colsum[FJ < 1 ? 1 : FJ] = {};
    const int lr = (l >> 4) << 2;
#pragma unroll
    for (int i = 0; i < FI; ++i) {
        const int rowl = wm * (BM / 2) + i * 16 + lr;
#pragma unroll
        for (int j = 0; j < FJ; ++j) {
            const int coll = n0 + wn * (BN / 2) + j * 16 + lc;

            float sc = 0.f, tc = 0.f, bi = 0.f;
            if constexpr (EPI == 1) {
                bi = (coll < 128) ? bias[coll] : bias2[coll - 128];
            } else if constexpr (EPI == 3 || EPI == 4 || EPI == 5) {
                sc = bng[coll] * rsqrtf(bnv[coll] + EPSBN);
                tc = bnb[coll] - bnm[coll] * sc;
                bi = bias[coll];
            }

#pragma unroll
            for (int r = 0; r < 4; ++r) {
                const int row = m0 + rowl + r;
                float vvv = acc[i][j][r];
                if constexpr (EPI == 1) {
                    float val = vvv + bi;
                    short hi = f2bf(val);
                    short lo = f2bf(val - bf2f(hi));
                    size_t rb = (size_t)row * 256;
                    if (coll < 128) {
                        short* qb_ = (short*)Cv;
                        qb_[rb + coll] = hi;
                        qb_[rb + 128 + coll] = lo;
                    } else {
                        short* kb_ = (short*)Cv2;
                        int c = coll - 128;
                        kb_[rb + c] = hi;
                        kb_[rb + 128 + c] = lo;
                    }
                } else if constexpr (EPI == 2) {
                    int bb = coll >> 12;
                    ((short*)Cv)[((size_t)bb * 256 + row) * 4096 + (coll & 4095)] = f2bf(vvv + bias[row]);
                } else if constexpr (EPI == 3) {
                    float g = sigmoidf_(fmaxf(sc * (vvv + bi) + tc, 0.f));
                    float fv = bf2f(aux[(size_t)row * 256 + coll]);
                    float yv = fv * g;
                    ((short*)Cv)[(size_t)row * 256 + coll] = f2bf(yv);
                    colsum[j] += yv;
                } else if constexpr (EPI == 4) {
                    float rv = fmaxf(sc * (vvv + bi) + tc, 0.f);
                    int bb = row >> 12, n = row & 4095;
                    int pr = bb * 4356 + ((n >> 6) + 1) * 66 + (n & 63) + 1;
                    ((short*)Cv)[(size_t)pr * 256 + coll] = f2bf(rv);
                } else if constexpr (EPI == 5) {
                    float rv = fmaxf(sc * (vvv + bi) + tc, 0.f);
                    ((short*)Cv)[(size_t)row * 256 + coll] = f2bf(rv);
                } else if constexpr (EPI == 6) {
                    float s6 = bng[row] * rsqrtf(bnv[row] + EPSBN);
                    float t6 = bnb[row] - bnm[row] * s6;
                    int bb = coll >> 12;
                    float yl = fmaxf(s6 * (vvv + bias[row]) + t6, 0.f);
                    float sg = sigmoidf_(yl + yrp[bb * 256 + row]);
                    float fv = bf2f(aux[(size_t)coll * 256 + row]);
                    ((float*)Cv)[((size_t)bb * 256 + row) * 4096 + (coll & 4095)] = fv * sg;
                }
            }
        }
    }

    // ---- EPI 3: fused pool stage 1 — per-block column sums -> Cv2 ----
    if constexpr (EPI == 3) {
        float* lsum = (float*)lsA;   // [64 cols][8 partials], 2 KB
#pragma unroll
        for (int j = 0; j < FJ; ++j) {
            int cl = wn * (BN / 2) + j * 16 + lc;
            lsum[cl * 8 + wm * 4 + ks] = colsum[j];
        }
        __syncthreads();
        if (tid < BN) {
            float s = 0.f;
#pragma unroll
            for (int u = 0; u < 8; ++u) s += lsum[tid * 8 + u];
            ((float*)Cv2)[(size_t)blockIdx.y * 256 + n0 + tid] = s;
        }
    }
}

// ---------------------------------------------------------------------------
// Flash attention v3: swapped QK + K-ROW-PERMUTED staging (no P transpose).
// 512 thr / 8 waves / 32 q per wave / 256 q per block.
// Grid 256 = 16 qblk x 16 combos (batch*4+kvq); kv-quarter, 32 iters.
// LDS K-slot m holds global kv row g(m) = ((m>>2)&3)*8 + (m>>4)*4 + (m&3).
// ---------------------------------------------------------------------------
__global__ __launch_bounds__(512, 2) void flash_k(
    const short* __restrict__ Q, const short* __restrict__ K,
    const short* __restrict__ V, short* __restrict__ Op, float* __restrict__ lp)
{
    __shared__ alignas(16) short smem[32768];
    // BYTES: K dbuf [0, 32768) | V dbuf [32768, 65536)

    const int tid = threadIdx.x;
    const int l = tid & 63;
    const int wv = tid >> 6;              // 0..7
    const int bid = blockIdx.x;
    const int combo = bid & 15;           // batch*4 + kvq
    const int batch = combo >> 2;
    const int kvq = combo & 3;
    const int q0 = (bid >> 4) * 256;
    const int kv0 = kvq * 1024;

    const short* Qb = Q + (size_t)batch * 4096 * 256;
    const short* Kb = K + (size_t)batch * 4096 * 256;
    const short* Vb = V + (size_t)batch * 256 * 4096;

    const int lc = l & 15, ks = l >> 4;

    // ---- Q fragments direct from global (B-operand: col=q=lc, k-chunk=ks) ----
    bf16x8 bq[2][8];
#pragma unroll
    for (int f = 0; f < 2; ++f)
#pragma unroll
        for (int cc = 0; cc < 8; ++cc)
            bq[f][cc] = *(const bf16x8*)(Qb +
                (size_t)(q0 + wv * 32 + f * 16 + lc) * 256 + cc * 32 + ks * 8);

    // ---- K/V staging (K rows permuted by g(slot)) ----
    const short* ksrc[2]; short* kdst[2];
    const short* vsrc[2]; short* vdst[2];
#pragma unroll
    for (int i = 0; i < 2; ++i) {
        int slot = wv * 4 + i * 2 + (l >> 5);
        int grow = ((slot >> 2) & 3) * 8 + (slot >> 4) * 4 + (slot & 3);
        int s = l & 31;
        int g = s ^ (slot & 7);
        ksrc[i] = Kb + (size_t)(kv0 + grow) * 256 + g * 8;
        kdst[i] = smem + wv * 1024 + i * 512;
        int c = wv * 32 + i * 16 + (l >> 2);
        int sv = l & 3;
        int gv = sv ^ ((c >> 1) & 3);
        vsrc[i] = Vb + (size_t)c * 4096 + kv0 + gv * 8;
        vdst[i] = smem + 16384 + wv * 1024 + i * 512;
    }
    auto stageKV = [&](int buf, int t) {
#pragma unroll
        for (int i = 0; i < 2; ++i) gl_lds16(ksrc[i] + (size_t)t * 8192, kdst[i] + buf * 8192);
#pragma unroll
        for (int i = 0; i < 2; ++i) gl_lds16(vsrc[i] + t * 32, vdst[i] + buf * 8192);
    };

    stageKV(0, 0);
    __syncthreads();

    const int kro = lc * 512;
    const int kxr = lc & 7;
    const int vb0 = lc * 64 + ((ks ^ ((lc >> 1) & 3)) << 4);

    bf16x8 ones;
#pragma unroll
    for (int e = 0; e < 8; ++e) ones[e] = (short)0x3F80;

    f32x4 acc_o[2][16] = {};
    f32x4 acc_l[2] = {};

    int cur = 0;
    for (int t = 0; t < 32; ++t) {
        if (t + 1 < 32) stageKV(cur ^ 1, t + 1);

        // ---- S^T = K·Q^T (hi/lo 3-term) ----
        const char* kb_ = (const char*)smem + cur * 16384;
        f32x4 s00 = {}, s01 = {}, s10 = {}, s11 = {};
        __builtin_amdgcn_s_setprio(1);
#pragma unroll
        for (int jc = 0; jc < 4; ++jc) {
#pragma unroll
            for (int kvf = 0; kvf < 2; ++kvf) {
                const char* rb_ = kb_ + kro + kvf * 8192;
                bf16x8 kh_ = *(const bf16x8*)(rb_ + ((((jc * 4) + ks) ^ kxr) << 4));
                bf16x8 kl_ = *(const bf16x8*)(rb_ + (((((jc + 4) * 4) + ks) ^ kxr) << 4));
                f32x4& sA = kvf ? s01 : s00;
                f32x4& sB = kvf ? s11 : s10;
                sA = __builtin_amdgcn_mfma_f32_16x16x32_bf16(kh_, bq[0][jc], sA, 0, 0, 0);
                sB = __builtin_amdgcn_mfma_f32_16x16x32_bf16(kh_, bq[1][jc], sB, 0, 0, 0);
                sA = __builtin_amdgcn_mfma_f32_16x16x32_bf16(kl_, bq[0][jc], sA, 0, 0, 0);
                sB = __builtin_amdgcn_mfma_f32_16x16x32_bf16(kl_, bq[1][jc], sB, 0, 0, 0);
                sA = __builtin_amdgcn_mfma_f32_16x16x32_bf16(kh_, bq[0][jc + 4], sA, 0, 0, 0);
                sB = __builtin_amdgcn_mfma_f32_16x16x32_bf16(kh_, bq[1][jc + 4], sB, 0, 0, 0);
            }
        }
        __builtin_amdgcn_s_setprio(0);

        // ---- P = exp(S): registers already in PV A-operand order ----
        bf16x8 pa[2];
#pragma unroll
        for (int f = 0; f < 2; ++f) {
            const f32x4& sa = f ? s10 : s00;   // kv = ks*8 + 0..3
            const f32x4& sb = f ? s11 : s01;   // kv = ks*8 + 4..7
            union { int i4[4]; bf16x8 v; } un;
            un.i4[0] = pk2(__expf(sa[0]), __expf(sa[1]));
            un.i4[1] = pk2(__expf(sa[2]), __expf(sa[3]));
            un.i4[2] = pk2(__expf(sb[0]), __expf(sb[1]));
            un.i4[3] = pk2(__expf(sb[2]), __expf(sb[3]));
            pa[f] = un.v;
        }

        // ---- O += P·V ; l += P·1 ----
        const char* vbb = (const char*)smem + 32768 + cur * 16384;
        __builtin_amdgcn_s_setprio(1);
#pragma unroll
        for (int j = 0; j < 16; ++j) {
            bf16x8 vv = *(const bf16x8*)(vbb + vb0 + j * 1024);
            acc_o[0][j] = __builtin_amdgcn_mfma_f32_16x16x32_bf16(pa[0], vv, acc_o[0][j], 0, 0, 0);
            acc_o[1][j] = __builtin_amdgcn_mfma_f32_16x16x32_bf16(pa[1], vv, acc_o[1][j], 0, 0, 0);
        }
        acc_l[0] = __builtin_amdgcn_mfma_f32_16x16x32_bf16(pa[0], ones, acc_l[0], 0, 0, 0);
        acc_l[1] = __builtin_amdgcn_mfma_f32_16x16x32_bf16(pa[1], ones, acc_l[1], 0, 0, 0);
        __builtin_amdgcn_s_setprio(0);
        __syncthreads();
        cur ^= 1;
    }

    // ---- store unnormalized bf16 partials ----
    short* Ob = Op + ((size_t)combo * 4096 + q0 + wv * 32) * 256;
#pragma unroll
    for (int f = 0; f < 2; ++f)
#pragma unroll
        for (int j = 0; j < 16; ++j)
#pragma unroll
            for (int r = 0; r < 4; ++r)
                Ob[(size_t)(f * 16 + ks * 4 + r) * 256 + j * 16 + lc] = f2bf(acc_o[f][j][r]);
    if (lc == 0) {
        float* lb = lp + (size_t)combo * 4096 + q0 + wv * 32;
#pragma unroll
        for (int f = 0; f < 2; ++f)
#pragma unroll
            for (int r = 0; r < 4; ++r)
                lb[f * 16 + ks * 4 + r] = acc_l[f][r];
    }
}

// featT = (sum of 4 bf16 kvq partials) / (sum of l), cast bf16.
__global__ __launch_bounds__(256) void combine_k(const short* __restrict__ Op,
                                                 const float* __restrict__ lp,
                                                 short* __restrict__ o)
{
    int idx = blockIdx.x * 256 + threadIdx.x;
    size_t e = (size_t)idx * 4;
    int row = (int)(e >> 8);            // (b, q)
    int batch = row >> 12, ql = row & 4095;
    int c = (int)(e & 255);
    size_t lbase = (size_t)batch * 4 * 4096 + ql;
    float li = 1.0f / (lp[lbase] + lp[lbase + 4096] + lp[lbase + 8192] + lp[lbase + 12288]);
    size_t base = ((size_t)(batch * 4) * 4096 + ql) * 256 + c;
    const short4 a = *(const short4*)(Op + base);
    const short4 b = *(const short4*)(Op + base + 1048576);
    const short4 cc = *(const short4*)(Op + base + 2097152);
    const short4 d = *(const short4*)(Op + base + 3145728);
    short4 o4;
    o4.x = f2bf((bf2f(a.x) + bf2f(b.x) + bf2f(cc.x) + bf2f(d.x)) * li);
    o4.y = f2bf((bf2f(a.y) + bf2f(b.y) + bf2f(cc.y) + bf2f(d.y)) * li);
    o4.z = f2bf((bf2f(a.z) + bf2f(b.z) + bf2f(cc.z) + bf2f(d.z)) * li);
    o4.w = f2bf((bf2f(a.w) + bf2f(b.w) + bf2f(cc.w) + bf2f(d.w)) * li);
    *(short4*)(o + (size_t)row * 256 + c) = o4;
}

// ---------------------------------------------------------------------------
// Merged setup kernel, grid 5648:
//  [0,1024)    : x transpose -> xT2 [(b,n)][512] bf16 [xh xl]
//  [1024,4608) : weight converts (wqk3 hi-lo-hi, 4 plain cvts, l2w permute)
//  [4608,5648) : zero t1pad halo borders (t1pad does NOT alias Opart now)
// ---------------------------------------------------------------------------
__global__ __launch_bounds__(256) void setup_k(
    const float* __restrict__ x,
    const float* __restrict__ wq, const float* __restrict__ wk,
    const float* __restrict__ wvp, const float* __restrict__ d1w,
    const float* __restrict__ l1w, const float* __restrict__ l3w,
    const float* __restrict__ l2w,
    short* __restrict__ xT2,
    short* __restrict__ wqk3, short* __restrict__ wvb, short* __restrict__ d1wb,
    short* __restrict__ l1wb, short* __restrict__ l3wb, short* __restrict__ w2b,
    short* __restrict__ t1pad)
{
    __shared__ float tsh[64][65];
    const int bb = blockIdx.x;
    const int tid = threadIdx.x;

    if (bb < 1024) {
        // ---- x transpose ----
        const int n0 = (bb & 63) * 64;
        const int c0 = ((bb >> 6) & 3) * 64;
        const int b = bb >> 8;
#pragma unroll
        for (int rep = 0; rep < 16; ++rep) {
            int idx = tid + rep * 256;
            int i = idx >> 6, j = idx & 63;
            tsh[i][j] = x[((size_t)(b * 256 + c0 + i)) * NPIX + n0 + j];
        }
        __syncthreads();
#pragma unroll
        for (int rep = 0; rep < 16; ++rep) {
            int idx = tid + rep * 256;
            int i = idx >> 6, j = idx & 63;
            float v = tsh[j][i];
            short hi = f2bf(v);
            short lo = f2bf(v - bf2f(hi));
            size_t rb = ((size_t)(b * NPIX + n0 + i)) * 512;
            xT2[rb + c0 + j] = hi;
            xT2[rb + 256 + c0 + j] = lo;
        }
    } else if (bb < 1280) {
        // ---- wq/wk hi-lo-hi ----
        int idx = (bb - 1024) * 256 + tid;
        int o = idx >> 8, c = idx & 255;
        const float* src = (o < 128) ? wq : wk;
        float v = src[(o & 127) * 256 + c];
        short hi = f2bf(v);
        short lo = f2bf(v - bf2f(hi));
        size_t rb = (size_t)o * 768;
        wqk3[rb + c] = hi;
        wqk3[rb + 256 + c] = lo;
        wqk3[rb + 512 + c] = hi;
    } else if (bb < 2304) {
        // ---- 4 plain weight cvts ----
        int g = (bb - 1280) >> 8;
        int i = ((bb - 1280) & 255) * 256 + tid;
        const float* s = g == 0 ? wvp : g == 1 ? d1w : g == 2 ? l1w : l3w;
        short* d = g == 0 ? wvb : g == 1 ? d1wb : g == 2 ? l1wb : l3wb;
        d[i] = f2bf(s[i]);
    } else if (bb < 4608) {
        // ---- l2w permute: w2[t][co][ci] ----
        int idx = (bb - 2304) * 256 + tid;
        int t = idx >> 16;
        int rem = idx & 65535;
        int co = rem >> 8, ci = rem & 255;
        w2b[idx] = f2bf(l2w[((size_t)(co * 256 + ci)) * 9 + t]);
    } else {
        // ---- t1pad halo-border zeroing: 260 border pixels x 4 batches ----
        int bi = bb - 4608;               // 0..1039
        int batch = bi / 260;
        int p = bi - batch * 260;
        int r, c;
        if (p < 66)      { r = 0;  c = p; }
        else if (p < 132){ r = 65; c = p - 66; }
        else {
            int p2 = p - 132;             // 0..127
            r = 1 + (p2 & 63);
            c = (p2 < 64) ? 0 : 65;
        }
        t1pad[((size_t)batch * 4356 + r * 66 + c) * 256 + tid] = 0;
    }
}

// ---------------------------------------------------------------------------
// SE branch with fused pool stage 2: pooled from 32 per-block partials.
// ---------------------------------------------------------------------------
__global__ __launch_bounds__(256) void se_k(
    const float* __restrict__ pp2,
    const float* __restrict__ r1w, const float* __restrict__ r1b,
    const float* __restrict__ g, const float* __restrict__ bb,
    const float* __restrict__ m, const float* __restrict__ vv,
    const float* __restrict__ r2w, const float* __restrict__ r2b,
    float* __restrict__ yr)
{
    const int b = blockIdx.x;
    const int tid = threadIdx.x;
    __shared__ float p[256], hbuf[128];
    float s0 = 0.f;
#pragma unroll
    for (int k = 0; k < 32; ++k)
        s0 += pp2[(size_t)(b * 32 + k) * 256 + tid];
    p[tid] = s0 * (1.0f / NPIX);
    __syncthreads();
    if (tid < 128) {
        float a = r1b[tid];
        for (int ci = 0; ci < 256; ++ci) a = fmaf(r1w[tid * 256 + ci], p[ci], a);
        float s = g[tid] * rsqrtf(vv[tid] + EPSBN);
        float t = bb[tid] - m[tid] * s;
        hbuf[tid] = fmaxf(s * a + t, 0.f);
    }
    __syncthreads();
    float a = r2b[tid];
    for (int c2 = 0; c2 < 128; ++c2) a = fmaf(r2w[tid * 128 + c2], hbuf[c2], a);
    yr[b * 256 + tid] = a;
}

// ---------------------------------------------------------------------------
extern "C" void kernel_launch(void* const* d_in, const int* in_sizes, int n_in,
                              void* d_out, int out_size, void* d_ws, size_t ws_size,
                              hipStream_t stream)
{
    const float* x    = (const float*)d_in[0];
    const float* wq   = (const float*)d_in[1];
    const float* bq   = (const float*)d_in[2];
    const float* wk   = (const float*)d_in[3];
    const float* bk   = (const float*)d_in[4];
    const float* wvp  = (const float*)d_in[5];
    const float* bv   = (const float*)d_in[6];
    const float* d1w  = (const float*)d_in[7];
    const float* d1b  = (const float*)d_in[8];
    const float* bn1g = (const float*)d_in[9];
    const float* bn1b = (const float*)d_in[10];
    const float* bn1m = (const float*)d_in[11];
    const float* bn1v = (const float*)d_in[12];
    const float* lbn1g = (const float*)d_in[13];
    const float* lbn1b = (const float*)d_in[14];
    const float* lbn1m = (const float*)d_in[15];
    const float* lbn1v = (const float*)d_in[16];
    const float* lbn2g = (const float*)d_in[17];
    const float* lbn2b = (const float*)d_in[18];
    const float* lbn2m = (const float*)d_in[19];
    const float* lbn2v = (const float*)d_in[20];
    const float* lbn3g = (const float*)d_in[21];
    const float* lbn3b = (const float*)d_in[22];
    const float* lbn3m = (const float*)d_in[23];
    const float* lbn3v = (const float*)d_in[24];
    const float* l1w  = (const float*)d_in[25];
    const float* l1b  = (const float*)d_in[26];
    const float* l2w  = (const float*)d_in[27];
    const float* l2b  = (const float*)d_in[28];
    const float* l3w  = (const float*)d_in[29];
    const float* l3b  = (const float*)d_in[30];
    const float* r1w  = (const float*)d_in[31];
    const float* r1b  = (const float*)d_in[32];
    const float* rbng = (const float*)d_in[33];
    const float* rbnb = (const float*)d_in[34];
    const float* rbnm = (const float*)d_in[35];
    const float* rbnv = (const float*)d_in[36];
    const float* r2w  = (const float*)d_in[37];
    const float* r2b  = (const float*)d_in[38];

    float* out = (float*)d_out;
    char* wsb = (char*)d_ws;

    // ---- workspace layout ----
    short* xT2  = (short*)(wsb);                    // 0-16 MB (dead after proj)
    short* qbuf = (short*)(wsb + (24ull << 20));    // 24-32
    short* kbuf = (short*)(wsb + (32ull << 20));    // 32-40
    short* vbuf = (short*)(wsb + (40ull << 20));    // 40-48
    short* Opart= (short*)(wsb + (48ull << 20));    // 48-80 bf16 [16][4096][256]
    short* t1pad= (short*)(wsb + (80ull << 20));    // 80-88.51 MB (no aliasing!)
    short* t2T  = (short*)(wsb + (89ull << 20));    // 89-97 MB
    short* featT= (short*)(wsb + (112ull << 20));   // 112-120
    float* lpart= (float*)(wsb + (120ull << 20));   // [16][4096] 256 KB
    short* yT   = (short*)(wsb + (48ull << 20));    // overlay Opart post-combine
    short* wqk3 = (short*)(wsb + (121ull << 20));   // 384 KB
    short* wvb  = wqk3 + 196608;                    // 128 KB each
    short* d1wb = wvb + 65536;
    short* l1wb = d1wb + 65536;
    short* l3wb = l1wb + 65536;
    short* w2b  = l3wb + 65536;                     // 1.125 MB
    float* yrb  = (float*)(wsb + (123ull << 20) + (512ull << 10));
    float* ppart2 = yrb + 1024;                     // [128][256] 128 KB

    dim3 blk(256);

    // ---- merged setup (transpose + weight prep + t1pad border zero) ----
    setup_k<<<5648, blk, 0, stream>>>(x, wq, wk, wvp, d1w, l1w, l3w, l2w,
                                      xT2, wqk3, wvb, d1wb, l1wb, l3wb, w2b, t1pad);

    // ---- projections ----
    gbt_k<1, 128, 64><<<dim3(4, 128), blk, 0, stream>>>(xT2, 512, wqk3, 768, qbuf, kbuf, 768,
        bq, bk, nullptr, nullptr, nullptr, nullptr, nullptr, nullptr);
    gbt_k<2, 64, 128><<<dim3(128, 4), blk, 0, stream>>>(wvb, 256, xT2, 512, vbuf, nullptr, 256,
        bv, nullptr, nullptr, nullptr, nullptr, nullptr, nullptr, nullptr);

    // ---- fused flash attention (kv-quarter bf16 partials) + combine ----
    flash_k<<<256, dim3(512), 0, stream>>>(qbuf, kbuf, vbuf, Opart, lpart);
    combine_k<<<4096, blk, 0, stream>>>(Opart, lpart, featT);

    // ---- gate: yT = feat * sigmoid(relu(bn1(d1(feat)))); fused pool s1 ----
    gbt_k<3, 128, 64><<<dim3(4, 128), blk, 0, stream>>>(featT, 256, d1wb, 256, yT, ppart2, 256,
        d1b, nullptr, bn1g, bn1b, bn1m, bn1v, featT, nullptr);

    // ---- SE branch (pool s2 fused into se) ----
    se_k<<<4, blk, 0, stream>>>(ppart2, r1w, r1b, rbng, rbnb, rbnm, rbnv, r2w, r2b, yrb);

    // ---- left branch ----
    gbt_k<4, 128, 64><<<dim3(4, 128), blk, 0, stream>>>(yT, 256, l1wb, 256, t1pad, nullptr, 256,
        l1b, nullptr, lbn1g, lbn1b, lbn1m, lbn1v, nullptr, nullptr);
    gbt_k<5, 128, 64><<<dim3(4, 128), blk, 0, stream>>>(t1pad, 256, w2b, 256, t2T, nullptr, 2304,
        l2b, nullptr, lbn2g, lbn2b, lbn2m, lbn2v, nullptr, nullptr);

    // ---- final: out = feat * sigmoid(relu(bn3(l3(t2))) + yr) ----
    gbt_k<6, 64, 128><<<dim3(128, 4), blk, 0, stream>>>(l3wb, 256, t2T, 256, out, nullptr, 256,
        l3b, nullptr, lbn3g, lbn3b, lbn3m, lbn3v, featT, yrb);
}